// Round 18
// baseline (527.151 us; speedup 1.0000x reference)
//
#include <hip/hip_runtime.h>

#define NUM_B 256
#define SEQ_L 100
#define NPIX  240000
#define KPAD  1024
#define BN    128
#define BK    128
#define NWG   1875   // NPIX / BN

typedef __attribute__((ext_vector_type(8))) short short8;
typedef __attribute__((ext_vector_type(4))) float f32x4;

static __device__ __forceinline__ unsigned short f2bf(float f) {
  unsigned int u = __builtin_bit_cast(unsigned int, f);
  u += 0x7fffu + ((u >> 16) & 1u);   // round-to-nearest-even
  return (unsigned short)(u >> 16);
}

// ---------------- Kernel 1 (fused): embedding-bag means + fc1 + fc2 -> h2 bf16 [256][1024]
// 1024 threads (16 waves). Measured ~36 us. Unchanged.
__global__ __launch_bounds__(1024) void embed_mlp_kernel(
    const int* __restrict__ bucket, const int* __restrict__ ids,
    const float* __restrict__ W100, const float* __restrict__ W10,
    const float* __restrict__ W0,
    const float* __restrict__ fc1_w, const float* __restrict__ fc1_b,
    const float* __restrict__ fc2_w, const float* __restrict__ fc2_b,
    unsigned short* __restrict__ h2out)
{
  __shared__ __align__(16) float xw[16][1000];  // per-wave partial sums (64 KB)
  __shared__ __align__(16) float xs[1000];
  __shared__ __align__(16) float h1s[200];
  __shared__ int sb[SEQ_L], sid[SEQ_L];
  __shared__ int cnt[16][3];
  __shared__ int cntT[3];

  const int row = blockIdx.x, tid = threadIdx.x;
  const int wid = tid >> 6, lane = tid & 63;

  if (tid < SEQ_L) {
    sb[tid]  = bucket[row * SEQ_L + tid];
    sid[tid] = ids[row * SEQ_L + tid];
  }
  __syncthreads();

  float acc0[8] = {0,0,0,0,0,0,0,0};
  float acc1[4] = {0,0,0,0};
  float acc2[4] = {0,0,0,0};
  int c0 = 0, c1 = 0, c2 = 0;

  for (int l = wid; l < SEQ_L; l += 16) {      // wave-uniform token
    const int b = sb[l];
    const long id = sid[l];
    if (b == 0) {
      ++c0; const float* r = W100 + id * 500;
      #pragma unroll
      for (int j = 0; j < 7; ++j) acc0[j] += r[lane + 64 * j];
      if (lane < 52) acc0[7] += r[lane + 448];
    } else if (b == 1) {
      ++c1; const float* r = W10 + id * 250;
      #pragma unroll
      for (int j = 0; j < 3; ++j) acc1[j] += r[lane + 64 * j];
      if (lane < 58) acc1[3] += r[lane + 192];
    } else {
      ++c2; const float* r = W0 + id * 250;
      #pragma unroll
      for (int j = 0; j < 3; ++j) acc2[j] += r[lane + 64 * j];
      if (lane < 58) acc2[3] += r[lane + 192];
    }
  }
  {
    float* xp = xw[wid];
    #pragma unroll
    for (int j = 0; j < 8; ++j) { int d = lane + 64 * j; if (d < 500) xp[d] = acc0[j]; }
    #pragma unroll
    for (int j = 0; j < 4; ++j) { int d = lane + 64 * j; if (d < 250) xp[500 + d] = acc1[j]; }
    #pragma unroll
    for (int j = 0; j < 4; ++j) { int d = lane + 64 * j; if (d < 250) xp[750 + d] = acc2[j]; }
    if (lane == 0) { cnt[wid][0] = c0; cnt[wid][1] = c1; cnt[wid][2] = c2; }
  }
  __syncthreads();
  if (tid < 3) { int s = 0; for (int w = 0; w < 16; ++w) s += cnt[w][tid]; cntT[tid] = s; }
  __syncthreads();
  if (tid < 1000) {
    float s = 0.f;
    #pragma unroll
    for (int w = 0; w < 16; ++w) s += xw[w][tid];
    const int bkt = tid < 500 ? 0 : (tid < 750 ? 1 : 2);
    const int c = cntT[bkt];
    xs[tid] = c ? s / (float)c : 0.f;
  }
  __syncthreads();

  const int g = tid >> 4, sl = tid & 15;       // 64 sixteen-lane groups

  for (int o = g; o < 200; o += 64) {
    const f32x4* wr = (const f32x4*)(fc1_w + o * 1000);
    const f32x4* xv = (const f32x4*)xs;
    float p = 0.f;
    for (int j = sl; j < 250; j += 16) {
      f32x4 a = xv[j], b = wr[j];
      p += a.x * b.x + a.y * b.y + a.z * b.z + a.w * b.w;
    }
    #pragma unroll
    for (int off = 8; off; off >>= 1) p += __shfl_down(p, off, 16);
    if (sl == 0) h1s[o] = fmaxf(p + fc1_b[o], 0.f);
  }
  __syncthreads();

  unsigned short* hrow = h2out + (long)row * KPAD;
  for (int o = g; o < 1000; o += 64) {
    const f32x4* wr = (const f32x4*)(fc2_w + o * 200);
    const f32x4* hv = (const f32x4*)h1s;
    float p = 0.f;
    #pragma unroll
    for (int j = sl; j < 50; j += 16) {
      f32x4 a = hv[j], b = wr[j];
      p += a.x * b.x + a.y * b.y + a.z * b.z + a.w * b.w;
    }
    #pragma unroll
    for (int off = 8; off; off >>= 1) p += __shfl_down(p, off, 16);
    if (sl == 0) hrow[o] = f2bf(fmaxf(p + fc2_b[o], 0.f));
  }
  if (tid < KPAD - 1000) hrow[1000 + tid] = 0;
}

// ---------------- Kernel 2: ratings = h2 @ out_w^T + out_b
// B-direct-to-register: the MFMA B-fragment is CONTIGUOUS in out_w (lane
// reads 32B straight), so B skips LDS entirely — no Bs buffer, no storeB,
// no bReg round-trip. A stays r11's dmaA (global_load_lds w16, pre-swizzled
// source). LDS 68KB -> 2 blocks/CU (launch_bounds (512,4), VGPR<=128):
// co-resident blocks cover barrier/compute-tail gaps (m114). K-edge kt=7:
// clamp k>=1000 to 0 — A's zero-padded cols kill those products.
__global__ __launch_bounds__(512, 4) void out_gemm_kernel(
    const unsigned short* __restrict__ h2,  // [256][1024] bf16 bits
    const float* __restrict__ out_w,        // [240000][1000] fp32
    const float* __restrict__ out_b,        // [240000]
    float* __restrict__ out)                // [256][240000]
{
  __shared__ __align__(16) unsigned char lds[69632];   // 68 KB: A 64KB; E reuse
  unsigned char* As = lds;             // [256 rows][256B] bf16, XOR-swizzled

  const int tid = threadIdx.x;

  // bijective XCD swizzle (nwg=1875, q=234, r=3)
  const int q = NWG / 8, r = NWG % 8;
  const int xcd = blockIdx.x & 7, bidx = blockIdx.x >> 3;
  const int wg = (xcd < r ? xcd * (q + 1) : r * (q + 1) + (xcd - r) * q) + bidx;
  const long n0 = (long)wg * BN;

  // A: 256 rows x 128 k bf16 = 64KB/kt, DMA'd global->LDS. Linear LDS dest;
  // source pre-swizzled so read-side XOR ((k16*16)^((rw&7)<<4)) recovers k16.
  auto dmaA = [&](int kt) {
    #pragma unroll
    for (int i = 0; i < 8; ++i) {
      const int c = tid + 512 * i;
      const int rw = c >> 4;
      const int k16s = (c & 15) ^ (rw & 7);
      const unsigned short* src = h2 + rw * KPAD + kt * BK + k16s * 8;
      __builtin_amdgcn_global_load_lds(
          (const __attribute__((address_space(1))) void*)src,
          (__attribute__((address_space(3))) void*)(As + c * 16),
          16, 0, 0);
    }
  };

  const int wid = tid >> 6, lane = tid & 63;
  const int wm = wid >> 2, wn = wid & 3;      // wave grid 2 (M) x 4 (N)
  const int lrow = lane & 15, lkg = lane >> 4;

  const f32x4 fz = {0.f, 0.f, 0.f, 0.f};
  f32x4 acc[8][2];
  #pragma unroll
  for (int m = 0; m < 8; ++m) { acc[m][0] = fz; acc[m][1] = fz; }

  // B fragment base pointers (row fixed per n; k advances per kt/kk)
  const float* Bp[2];
  #pragma unroll
  for (int n = 0; n < 2; ++n)
    Bp[n] = out_w + (n0 + wn * 32 + n * 16 + lrow) * 1000 + lkg * 8;

  auto compute = [&](int kt) {
    #pragma unroll
    for (int kk = 0; kk < 4; ++kk) {
      short8 bf[2];
      #pragma unroll
      for (int n = 0; n < 2; ++n) {
        int k = kt * BK + kk * 32;
        const float* p = (k + lkg * 8 < 1000) ? (Bp[n] + k) : (Bp[n] - lkg * 8);
        f32x4 lo = *(const f32x4*)p;
        f32x4 hi = *(const f32x4*)(p + 4);
        bf[n][0] = (short)f2bf(lo.x); bf[n][1] = (short)f2bf(lo.y);
        bf[n][2] = (short)f2bf(lo.z); bf[n][3] = (short)f2bf(lo.w);
        bf[n][4] = (short)f2bf(hi.x); bf[n][5] = (short)f2bf(hi.y);
        bf[n][6] = (short)f2bf(hi.z); bf[n][7] = (short)f2bf(hi.w);
      }
      #pragma unroll
      for (int m = 0; m < 8; ++m) {
        const int rr = wm * 128 + m * 16 + lrow;
        short8 af = *(const short8*)(As + rr * 256 + (((kk * 64) + lkg * 16) ^ ((rr & 7) << 4)));
        acc[m][0] = __builtin_amdgcn_mfma_f32_16x16x32_bf16(af, bf[0], acc[m][0], 0, 0, 0);
        acc[m][1] = __builtin_amdgcn_mfma_f32_16x16x32_bf16(af, bf[1], acc[m][1], 0, 0, 0);
      }
    }
  };

  // ---- main loop: 8 k-tiles. Top sync drains dmaA; B streams from global
  // inside compute; raw lgkm barrier guards As overwrite.
  dmaA(0);
  #pragma unroll 1
  for (int kt = 0; kt < 8; ++kt) {
    __syncthreads();                       // drains dmaA(kt); As ready
    compute(kt);                           // B: 16x 16B global loads + cvt + MFMA
    asm volatile("s_waitcnt lgkmcnt(0)" ::: "memory");
    __builtin_amdgcn_s_barrier();          // As readers done
    __builtin_amdgcn_sched_barrier(0);
    if (kt < 7) dmaA(kt + 1);
  }

  // ---- epilogue: stage 128x128 f32 chunks in LDS, then 512B-run NT stores.
  const float b0 = out_b[n0 + wn * 32 + lrow];
  const float b1 = out_b[n0 + wn * 32 + 16 + lrow];
  float* E = (float*)lds;            // [128][132] floats = 67,584 B (fits 68KB)
  #pragma unroll
  for (int half = 0; half < 2; ++half) {
    __syncthreads();
    if (wm == half) {
      #pragma unroll
      for (int m = 0; m < 8; ++m) {
        #pragma unroll
        for (int n = 0; n < 2; ++n) {
          const int col = wn * 32 + n * 16 + lrow;
          const float bias = n ? b1 : b0;
          #pragma unroll
          for (int rr = 0; rr < 4; ++rr) {
            const int rowl = m * 16 + lkg * 4 + rr;
            E[rowl * 132 + col] = acc[m][n][rr] + bias;
          }
        }
      }
    }
    __syncthreads();
    const int rbase = half * 128;
    #pragma unroll
    for (int s = 0; s < 8; ++s) {
      const int rowl = s * 16 + (tid >> 5);
      const int c = (tid & 31) * 4;
      f32x4 v = *(const f32x4*)(E + rowl * 132 + c);
      __builtin_nontemporal_store(v, (f32x4*)(out + (long)(rbase + rowl) * NPIX + n0 + c));
    }
  }
}

extern "C" void kernel_launch(void* const* d_in, const int* in_sizes, int n_in,
                              void* d_out, int out_size, void* d_ws, size_t ws_size,
                              hipStream_t stream) {
  const int*   bucket = (const int*)d_in[0];
  const int*   ids    = (const int*)d_in[1];
  const float* W100   = (const float*)d_in[2];
  const float* W10    = (const float*)d_in[3];
  const float* W0     = (const float*)d_in[4];
  const float* fc1w   = (const float*)d_in[5];
  const float* fc1b   = (const float*)d_in[6];
  const float* fc2w   = (const float*)d_in[7];
  const float* fc2b   = (const float*)d_in[8];
  const float* outw   = (const float*)d_in[9];
  const float* outb   = (const float*)d_in[10];
  float* out = (float*)d_out;
  unsigned short* h2w = (unsigned short*)d_ws;  // 256*1024*2B = 512 KB

  embed_mlp_kernel<<<NUM_B, 1024, 0, stream>>>(bucket, ids, W100, W10, W0,
                                               fc1w, fc1b, fc2w, fc2b, h2w);
  out_gemm_kernel<<<NWG, 512, 0, stream>>>(h2w, outw, outb, out);
}

// Round 19
// 392.466 us; speedup vs baseline: 1.3432x; 1.3432x over previous
//
#include <hip/hip_runtime.h>

#define NUM_B 256
#define SEQ_L 100
#define NPIX  240000
#define KPAD  1024
#define BN    64
#define BK    256     // per B-tile; consumed in two 128-k sub-phases
#define NWG   3750    // NPIX / BN

typedef __attribute__((ext_vector_type(8))) short short8;
typedef __attribute__((ext_vector_type(4))) float f32x4;

static __device__ __forceinline__ unsigned short f2bf(float f) {
  unsigned int u = __builtin_bit_cast(unsigned int, f);
  u += 0x7fffu + ((u >> 16) & 1u);   // round-to-nearest-even
  return (unsigned short)(u >> 16);
}

// ---------------- Kernel 1 (fused): embedding-bag means + fc1 + fc2 -> h2 bf16 [256][1024]
// 1024 threads (16 waves). Measured ~36 us. Unchanged.
__global__ __launch_bounds__(1024) void embed_mlp_kernel(
    const int* __restrict__ bucket, const int* __restrict__ ids,
    const float* __restrict__ W100, const float* __restrict__ W10,
    const float* __restrict__ W0,
    const float* __restrict__ fc1_w, const float* __restrict__ fc1_b,
    const float* __restrict__ fc2_w, const float* __restrict__ fc2_b,
    unsigned short* __restrict__ h2out)
{
  __shared__ __align__(16) float xw[16][1000];  // per-wave partial sums (64 KB)
  __shared__ __align__(16) float xs[1000];
  __shared__ __align__(16) float h1s[200];
  __shared__ int sb[SEQ_L], sid[SEQ_L];
  __shared__ int cnt[16][3];
  __shared__ int cntT[3];

  const int row = blockIdx.x, tid = threadIdx.x;
  const int wid = tid >> 6, lane = tid & 63;

  if (tid < SEQ_L) {
    sb[tid]  = bucket[row * SEQ_L + tid];
    sid[tid] = ids[row * SEQ_L + tid];
  }
  __syncthreads();

  float acc0[8] = {0,0,0,0,0,0,0,0};
  float acc1[4] = {0,0,0,0};
  float acc2[4] = {0,0,0,0};
  int c0 = 0, c1 = 0, c2 = 0;

  for (int l = wid; l < SEQ_L; l += 16) {      // wave-uniform token
    const int b = sb[l];
    const long id = sid[l];
    if (b == 0) {
      ++c0; const float* r = W100 + id * 500;
      #pragma unroll
      for (int j = 0; j < 7; ++j) acc0[j] += r[lane + 64 * j];
      if (lane < 52) acc0[7] += r[lane + 448];
    } else if (b == 1) {
      ++c1; const float* r = W10 + id * 250;
      #pragma unroll
      for (int j = 0; j < 3; ++j) acc1[j] += r[lane + 64 * j];
      if (lane < 58) acc1[3] += r[lane + 192];
    } else {
      ++c2; const float* r = W0 + id * 250;
      #pragma unroll
      for (int j = 0; j < 3; ++j) acc2[j] += r[lane + 64 * j];
      if (lane < 58) acc2[3] += r[lane + 192];
    }
  }
  {
    float* xp = xw[wid];
    #pragma unroll
    for (int j = 0; j < 8; ++j) { int d = lane + 64 * j; if (d < 500) xp[d] = acc0[j]; }
    #pragma unroll
    for (int j = 0; j < 4; ++j) { int d = lane + 64 * j; if (d < 250) xp[500 + d] = acc1[j]; }
    #pragma unroll
    for (int j = 0; j < 4; ++j) { int d = lane + 64 * j; if (d < 250) xp[750 + d] = acc2[j]; }
    if (lane == 0) { cnt[wid][0] = c0; cnt[wid][1] = c1; cnt[wid][2] = c2; }
  }
  __syncthreads();
  if (tid < 3) { int s = 0; for (int w = 0; w < 16; ++w) s += cnt[w][tid]; cntT[tid] = s; }
  __syncthreads();
  if (tid < 1000) {
    float s = 0.f;
    #pragma unroll
    for (int w = 0; w < 16; ++w) s += xw[w][tid];
    const int bkt = tid < 500 ? 0 : (tid < 750 ? 1 : 2);
    const int c = cntT[bkt];
    xs[tid] = c ? s / (float)c : 0.f;
  }
  __syncthreads();

  const int g = tid >> 4, sl = tid & 15;       // 64 sixteen-lane groups

  for (int o = g; o < 200; o += 64) {
    const f32x4* wr = (const f32x4*)(fc1_w + o * 1000);
    const f32x4* xv = (const f32x4*)xs;
    float p = 0.f;
    for (int j = sl; j < 250; j += 16) {
      f32x4 a = xv[j], b = wr[j];
      p += a.x * b.x + a.y * b.y + a.z * b.z + a.w * b.w;
    }
    #pragma unroll
    for (int off = 8; off; off >>= 1) p += __shfl_down(p, off, 16);
    if (sl == 0) h1s[o] = fmaxf(p + fc1_b[o], 0.f);
  }
  __syncthreads();

  unsigned short* hrow = h2out + (long)row * KPAD;
  for (int o = g; o < 1000; o += 64) {
    const f32x4* wr = (const f32x4*)(fc2_w + o * 200);
    const f32x4* hv = (const f32x4*)h1s;
    float p = 0.f;
    #pragma unroll
    for (int j = sl; j < 50; j += 16) {
      f32x4 a = hv[j], b = wr[j];
      p += a.x * b.x + a.y * b.y + a.z * b.z + a.w * b.w;
    }
    #pragma unroll
    for (int off = 8; off; off >>= 1) p += __shfl_down(p, off, 16);
    if (sl == 0) hrow[o] = f2bf(fmaxf(p + fc2_b[o], 0.f));
  }
  if (tid < KPAD - 1000) hrow[1000 + tid] = 0;
}

// ---------------- Kernel 2: ratings = h2 @ out_w^T + out_b
// r11 skeleton with BN=64/BK=256: each B-tile = 64 rows x 1KB CONTIGUOUS
// DRAM runs (2x the 512B runs that cap DRAM page efficiency), consumed in
// two 128-k sub-phases sharing r11's 64KB A buffer (dmaA per sub-phase,
// identical to r11's per-kt dmaA). storeB only on even sub-phases (half
// the round-trips). LDS = A 64KB + B 32KB = 96KB (proven size).
__global__ __launch_bounds__(512) void out_gemm_kernel(
    const unsigned short* __restrict__ h2,  // [256][1024] bf16 bits
    const float* __restrict__ out_w,        // [240000][1000] fp32
    const float* __restrict__ out_b,        // [240000]
    float* __restrict__ out)                // [256][240000]
{
  __shared__ __align__(16) unsigned char lds[98304];   // 96 KB
  unsigned char* As = lds;             // [256 rows][256B] bf16, XOR-swizzled
  unsigned char* Bs = lds + 65536;     // [64 rows][512B] bf16, XOR-swizzled

  const int tid = threadIdx.x;

  // bijective XCD swizzle (nwg=3750, q=468, r=6)
  const int q = NWG / 8, r = NWG % 8;
  const int xcd = blockIdx.x & 7, bidx = blockIdx.x >> 3;
  const int wg = (xcd < r ? xcd * (q + 1) : r * (q + 1) + (xcd - r) * q) + bidx;
  const long n0 = (long)wg * BN;

  const f32x4 fz = {0.f, 0.f, 0.f, 0.f};

  f32x4 bReg[8];

  // A: 256 rows x 128 k bf16 = 64KB per SUB-PHASE sp (= r11's kt). Linear
  // LDS dest; source pre-swizzled so read-side XOR ((k16*16)^((rw&7)<<4))
  // recovers element k16.
  auto dmaA = [&](int sp) {
    #pragma unroll
    for (int i = 0; i < 8; ++i) {
      const int c = tid + 512 * i;
      const int rw = c >> 4;
      const int k16s = (c & 15) ^ (rw & 7);
      const unsigned short* src = h2 + rw * KPAD + sp * 128 + k16s * 8;
      __builtin_amdgcn_global_load_lds(
          (const __attribute__((address_space(1))) void*)src,
          (__attribute__((address_space(3))) void*)(As + c * 16),
          16, 0, 0);
    }
  };
  // B: 64 rows x 256 k fp32 = 64KB per B-tile bt. Each row read as ONE
  // 1KB contiguous run (wave = 64 lanes x 16B covers a full row).
  auto loadB = [&](int bt) {
    #pragma unroll
    for (int i = 0; i < 8; ++i) {
      int c = tid + 512 * i;
      int rw = c >> 6, g4 = c & 63;
      int k = bt * BK + g4 * 4;
      bReg[i] = (k < 1000)
        ? __builtin_nontemporal_load((const f32x4*)(out_w + (n0 + rw) * 1000 + k))
        : fz;
    }
  };
  auto storeB = [&]() {
    #pragma unroll
    for (int i = 0; i < 8; ++i) {
      int c = tid + 512 * i;
      int rw = c >> 6, g4 = c & 63;
      ushort4 h;
      h.x = f2bf(bReg[i].x); h.y = f2bf(bReg[i].y);
      h.z = f2bf(bReg[i].z); h.w = f2bf(bReg[i].w);
      *(ushort4*)(Bs + rw * 512 + ((g4 * 8) ^ ((rw & 7) << 4))) = h;
    }
  };

  const int wid = tid >> 6, lane = tid & 63;
  const int wm = wid >> 1, wn = wid & 1;      // wave grid 4 (M) x 2 (N)
  const int lrow = lane & 15, lkg = lane >> 4;

  f32x4 acc[4][2];
  #pragma unroll
  for (int m = 0; m < 4; ++m) { acc[m][0] = fz; acc[m][1] = fz; }

  auto compute = [&](int sp) {
    const int kh = (sp & 1) * 256;            // byte offset of k-half in Bs row
    #pragma unroll
    for (int kk = 0; kk < 4; ++kk) {
      short8 bf[2];
      #pragma unroll
      for (int n = 0; n < 2; ++n) {
        int nr = wn * 32 + n * 16 + lrow;
        bf[n] = *(const short8*)(Bs + nr * 512 + ((kh + kk * 64 + lkg * 16) ^ ((nr & 7) << 4)));
      }
      #pragma unroll
      for (int m = 0; m < 4; ++m) {
        int rr = wm * 64 + m * 16 + lrow;
        short8 af = *(const short8*)(As + rr * 256 + (((kk * 64) + lkg * 16) ^ ((rr & 7) << 4)));
        acc[m][0] = __builtin_amdgcn_mfma_f32_16x16x32_bf16(af, bf[0], acc[m][0], 0, 0, 0);
        acc[m][1] = __builtin_amdgcn_mfma_f32_16x16x32_bf16(af, bf[1], acc[m][1], 0, 0, 0);
      }
    }
  };

  // ---- main loop: 8 sub-phases (4 B-tiles x 2 k-halves), r11 skeleton.
  dmaA(0); loadB(0);
  #pragma unroll 1
  for (int sp = 0; sp < 8; ++sp) {
    if (!(sp & 1)) storeB();         // B(bt): counted vmcnt waits bReg only
    __syncthreads();                 // drains dmaA(sp); tile ready in LDS
    if (!(sp & 1) && sp < 6) loadB((sp >> 1) + 1);  // 1KB-run stream, 2 sub-phases to drain
    compute(sp);
    asm volatile("s_waitcnt lgkmcnt(0)" ::: "memory");
    __builtin_amdgcn_s_barrier();    // As/Bs readers done; stream rides over
    __builtin_amdgcn_sched_barrier(0);
    if (sp < 7) dmaA(sp + 1);
  }

  // ---- epilogue: two 128-row LDS-transpose passes, 256B-run plain stores
  const float b0 = out_b[n0 + wn * 32 + lrow];
  const float b1 = out_b[n0 + wn * 32 + 16 + lrow];
  float* E = (float*)lds;            // [128][68] floats = 34,816 B
  #pragma unroll
  for (int half = 0; half < 2; ++half) {
    __syncthreads();
    if ((wm >> 1) == half) {
      #pragma unroll
      for (int m = 0; m < 4; ++m) {
        #pragma unroll
        for (int n = 0; n < 2; ++n) {
          const int col = wn * 32 + n * 16 + lrow;
          const float bias = n ? b1 : b0;
          #pragma unroll
          for (int rr = 0; rr < 4; ++rr) {
            const int rowl = (wm & 1) * 64 + m * 16 + lkg * 4 + rr;
            E[rowl * 68 + col] = acc[m][n][rr] + bias;
          }
        }
      }
    }
    __syncthreads();
    const int rbase = half * 128;
    #pragma unroll
    for (int s = 0; s < 4; ++s) {
      const int idx = tid + 512 * s;
      const int rowl = idx >> 4;
      const int c = (idx & 15) * 4;
      f32x4 v = *(const f32x4*)(E + rowl * 68 + c);
      *(f32x4*)(out + (long)(rbase + rowl) * NPIX + n0 + c) = v;  // plain store
    }
  }
}

extern "C" void kernel_launch(void* const* d_in, const int* in_sizes, int n_in,
                              void* d_out, int out_size, void* d_ws, size_t ws_size,
                              hipStream_t stream) {
  const int*   bucket = (const int*)d_in[0];
  const int*   ids    = (const int*)d_in[1];
  const float* W100   = (const float*)d_in[2];
  const float* W10    = (const float*)d_in[3];
  const float* W0     = (const float*)d_in[4];
  const float* fc1w   = (const float*)d_in[5];
  const float* fc1b   = (const float*)d_in[6];
  const float* fc2w   = (const float*)d_in[7];
  const float* fc2b   = (const float*)d_in[8];
  const float* outw   = (const float*)d_in[9];
  const float* outb   = (const float*)d_in[10];
  float* out = (float*)d_out;
  unsigned short* h2w = (unsigned short*)d_ws;  // 256*1024*2B = 512 KB

  embed_mlp_kernel<<<NUM_B, 1024, 0, stream>>>(bucket, ids, W100, W10, W0,
                                               fc1w, fc1b, fc2w, fc2b, h2w);
  out_gemm_kernel<<<NWG, 512, 0, stream>>>(h2w, outw, outb, out);
}

// Round 20
// 319.163 us; speedup vs baseline: 1.6517x; 1.2297x over previous
//
#include <hip/hip_runtime.h>

#define NUM_B 256
#define SEQ_L 100
#define NPIX  240000
#define KPAD  1024
#define BN    128
#define BK    128
#define NWG   1875   // NPIX / BN

typedef __attribute__((ext_vector_type(8))) short short8;
typedef __attribute__((ext_vector_type(4))) float f32x4;

static __device__ __forceinline__ unsigned short f2bf(float f) {
  unsigned int u = __builtin_bit_cast(unsigned int, f);
  u += 0x7fffu + ((u >> 16) & 1u);   // round-to-nearest-even
  return (unsigned short)(u >> 16);
}

// ---------------- Kernel 1 (fused): embedding-bag means + fc1 + fc2 -> h2 bf16 [256][1024]
// 1024 threads (16 waves). Measured ~36 us.
__global__ __launch_bounds__(1024) void embed_mlp_kernel(
    const int* __restrict__ bucket, const int* __restrict__ ids,
    const float* __restrict__ W100, const float* __restrict__ W10,
    const float* __restrict__ W0,
    const float* __restrict__ fc1_w, const float* __restrict__ fc1_b,
    const float* __restrict__ fc2_w, const float* __restrict__ fc2_b,
    unsigned short* __restrict__ h2out)
{
  __shared__ __align__(16) float xw[16][1000];  // per-wave partial sums (64 KB)
  __shared__ __align__(16) float xs[1000];
  __shared__ __align__(16) float h1s[200];
  __shared__ int sb[SEQ_L], sid[SEQ_L];
  __shared__ int cnt[16][3];
  __shared__ int cntT[3];

  const int row = blockIdx.x, tid = threadIdx.x;
  const int wid = tid >> 6, lane = tid & 63;

  if (tid < SEQ_L) {
    sb[tid]  = bucket[row * SEQ_L + tid];
    sid[tid] = ids[row * SEQ_L + tid];
  }
  __syncthreads();

  float acc0[8] = {0,0,0,0,0,0,0,0};
  float acc1[4] = {0,0,0,0};
  float acc2[4] = {0,0,0,0};
  int c0 = 0, c1 = 0, c2 = 0;

  for (int l = wid; l < SEQ_L; l += 16) {      // wave-uniform token
    const int b = sb[l];
    const long id = sid[l];
    if (b == 0) {
      ++c0; const float* r = W100 + id * 500;
      #pragma unroll
      for (int j = 0; j < 7; ++j) acc0[j] += r[lane + 64 * j];
      if (lane < 52) acc0[7] += r[lane + 448];
    } else if (b == 1) {
      ++c1; const float* r = W10 + id * 250;
      #pragma unroll
      for (int j = 0; j < 3; ++j) acc1[j] += r[lane + 64 * j];
      if (lane < 58) acc1[3] += r[lane + 192];
    } else {
      ++c2; const float* r = W0 + id * 250;
      #pragma unroll
      for (int j = 0; j < 3; ++j) acc2[j] += r[lane + 64 * j];
      if (lane < 58) acc2[3] += r[lane + 192];
    }
  }
  {
    float* xp = xw[wid];
    #pragma unroll
    for (int j = 0; j < 8; ++j) { int d = lane + 64 * j; if (d < 500) xp[d] = acc0[j]; }
    #pragma unroll
    for (int j = 0; j < 4; ++j) { int d = lane + 64 * j; if (d < 250) xp[500 + d] = acc1[j]; }
    #pragma unroll
    for (int j = 0; j < 4; ++j) { int d = lane + 64 * j; if (d < 250) xp[750 + d] = acc2[j]; }
    if (lane == 0) { cnt[wid][0] = c0; cnt[wid][1] = c1; cnt[wid][2] = c2; }
  }
  __syncthreads();
  if (tid < 3) { int s = 0; for (int w = 0; w < 16; ++w) s += cnt[w][tid]; cntT[tid] = s; }
  __syncthreads();
  if (tid < 1000) {
    float s = 0.f;
    #pragma unroll
    for (int w = 0; w < 16; ++w) s += xw[w][tid];
    const int bkt = tid < 500 ? 0 : (tid < 750 ? 1 : 2);
    const int c = cntT[bkt];
    xs[tid] = c ? s / (float)c : 0.f;
  }
  __syncthreads();

  const int g = tid >> 4, sl = tid & 15;       // 64 sixteen-lane groups

  for (int o = g; o < 200; o += 64) {
    const f32x4* wr = (const f32x4*)(fc1_w + o * 1000);
    const f32x4* xv = (const f32x4*)xs;
    float p = 0.f;
    for (int j = sl; j < 250; j += 16) {
      f32x4 a = xv[j], b = wr[j];
      p += a.x * b.x + a.y * b.y + a.z * b.z + a.w * b.w;
    }
    #pragma unroll
    for (int off = 8; off; off >>= 1) p += __shfl_down(p, off, 16);
    if (sl == 0) h1s[o] = fmaxf(p + fc1_b[o], 0.f);
  }
  __syncthreads();

  unsigned short* hrow = h2out + (long)row * KPAD;
  for (int o = g; o < 1000; o += 64) {
    const f32x4* wr = (const f32x4*)(fc2_w + o * 200);
    const f32x4* hv = (const f32x4*)h1s;
    float p = 0.f;
    #pragma unroll
    for (int j = sl; j < 50; j += 16) {
      f32x4 a = hv[j], b = wr[j];
      p += a.x * b.x + a.y * b.y + a.z * b.z + a.w * b.w;
    }
    #pragma unroll
    for (int off = 8; off; off >>= 1) p += __shfl_down(p, off, 16);
    if (sl == 0) hrow[o] = f2bf(fmaxf(p + fc2_b[o], 0.f));
  }
  if (tid < KPAD - 1000) hrow[1000 + tid] = 0;
}

// ---------------- Kernel 2: ratings = h2 @ out_w^T + out_b
// r12 exact (best measured: gemm ~284us): BM=256/BN=128/BK=128, 96KB LDS,
// dmaA via global_load_lds w16 (pre-swizzled source), 1-deep B prefetch,
// NT B-loads, NT epilogue stores. Barrier-1 = __syncthreads (drains dmaA);
// barrier-2 = raw s_barrier (lgkm only; B prefetch rides across).
__global__ __launch_bounds__(512) void out_gemm_kernel(
    const unsigned short* __restrict__ h2,  // [256][1024] bf16 bits
    const float* __restrict__ out_w,        // [240000][1000] fp32
    const float* __restrict__ out_b,        // [240000]
    float* __restrict__ out)                // [256][240000]
{
  __shared__ __align__(16) unsigned char lds[98304];   // 96 KB
  unsigned char* As = lds;             // [256 rows][256B] bf16, XOR-swizzled
  unsigned char* Bs = lds + 65536;     // [128 rows][256B] bf16, XOR-swizzled

  const int tid = threadIdx.x;

  // bijective XCD swizzle (nwg=1875, q=234, r=3)
  const int q = NWG / 8, r = NWG % 8;
  const int xcd = blockIdx.x & 7, bidx = blockIdx.x >> 3;
  const int wg = (xcd < r ? xcd * (q + 1) : r * (q + 1) + (xcd - r) * q) + bidx;
  const long n0 = (long)wg * BN;

  const f32x4 fz = {0.f, 0.f, 0.f, 0.f};

  f32x4 bReg[8];

  // A: 256 rows x 128 k bf16 = 64KB/kt, DMA'd global->LDS.
  // Linear LDS dest (c*16); global source pre-swizzled so the read-side XOR
  // ((k16*16)^((rw&7)<<4)) recovers element k16.
  auto dmaA = [&](int kt) {
    #pragma unroll
    for (int i = 0; i < 8; ++i) {
      const int c = tid + 512 * i;
      const int rw = c >> 4;
      const int k16s = (c & 15) ^ (rw & 7);
      const unsigned short* src = h2 + rw * KPAD + kt * BK + k16s * 8;
      __builtin_amdgcn_global_load_lds(
          (const __attribute__((address_space(1))) void*)src,
          (__attribute__((address_space(3))) void*)(As + c * 16),
          16, 0, 0);
    }
  };
  // B: 128 rows x 128 k fp32 = 64KB/kt. 32 lanes read 512B contiguous per row.
  auto loadB = [&](int k0) {
    #pragma unroll
    for (int i = 0; i < 8; ++i) {
      int c = tid + 512 * i;
      int n = c >> 5, qq = c & 31;
      int k = k0 + qq * 4;
      bReg[i] = (k < 1000)
        ? __builtin_nontemporal_load((const f32x4*)(out_w + (long)(n0 + n) * 1000 + k))
        : fz;
    }
  };
  auto storeB = [&]() {
    #pragma unroll
    for (int i = 0; i < 8; ++i) {
      int c = tid + 512 * i;
      int n = c >> 5, qq = c & 31;
      ushort4 h;
      h.x = f2bf(bReg[i].x); h.y = f2bf(bReg[i].y);
      h.z = f2bf(bReg[i].z); h.w = f2bf(bReg[i].w);
      *(ushort4*)(Bs + n * 256 + ((qq * 8) ^ ((n & 7) << 4))) = h;
    }
  };

  const int wid = tid >> 6, lane = tid & 63;
  const int wm = wid >> 2, wn = wid & 3;      // wave grid 2 (M) x 4 (N)
  const int lrow = lane & 15, lkg = lane >> 4;

  f32x4 acc[8][2];
  #pragma unroll
  for (int m = 0; m < 8; ++m) { acc[m][0] = fz; acc[m][1] = fz; }

  // ---- main loop: 8 k-tiles. Barrier-1 = __syncthreads (drains dmaA);
  // barrier-2 = raw s_barrier (B-loads stay in flight).
  dmaA(0); loadB(0);
  #pragma unroll 1
  for (int kt = 0; kt < 8; ++kt) {
    storeB();                        // counted vmcnt: waits bReg, not dmaA queue
    __syncthreads();                 // drains dmaA(kt); tile kt ready in LDS
    if (kt < 7) loadB((kt + 1) * BK);           // B prefetch streams under MFMA
    #pragma unroll
    for (int kk = 0; kk < 4; ++kk) {
      short8 bf[2];
      #pragma unroll
      for (int n = 0; n < 2; ++n) {
        int nr = wn * 32 + n * 16 + lrow;
        bf[n] = *(const short8*)(Bs + nr * 256 + (((kk * 64) + lkg * 16) ^ ((nr & 7) << 4)));
      }
      #pragma unroll
      for (int m = 0; m < 8; ++m) {
        int rr = wm * 128 + m * 16 + lrow;
        short8 af = *(const short8*)(As + rr * 256 + (((kk * 64) + lkg * 16) ^ ((rr & 7) << 4)));
        acc[m][0] = __builtin_amdgcn_mfma_f32_16x16x32_bf16(af, bf[0], acc[m][0], 0, 0, 0);
        acc[m][1] = __builtin_amdgcn_mfma_f32_16x16x32_bf16(af, bf[1], acc[m][1], 0, 0, 0);
      }
    }
    // raw barrier: LDS readers done (lgkm), but do NOT drain vmcnt —
    // loadB(kt+1) keeps streaming across it.
    asm volatile("s_waitcnt lgkmcnt(0)" ::: "memory");
    __builtin_amdgcn_s_barrier();
    __builtin_amdgcn_sched_barrier(0);          // keep dmaA below the barrier
    if (kt < 7) dmaA(kt + 1);                   // overwrite As (readers done)
  }

  // epilogue: stage 128x128 f32 chunks in LDS, then 512B-run NT stores.
  const float b0 = out_b[n0 + wn * 32 + lrow];
  const float b1 = out_b[n0 + wn * 32 + 16 + lrow];
  float* E = (float*)lds;            // [128][132] floats = 67,584 B
  #pragma unroll
  for (int half = 0; half < 2; ++half) {
    __syncthreads();
    if (wm == half) {
      #pragma unroll
      for (int m = 0; m < 8; ++m) {
        #pragma unroll
        for (int n = 0; n < 2; ++n) {
          const int col = wn * 32 + n * 16 + lrow;
          const float bias = n ? b1 : b0;
          #pragma unroll
          for (int rr = 0; rr < 4; ++rr) {
            const int rowl = m * 16 + lkg * 4 + rr;
            E[rowl * 132 + col] = acc[m][n][rr] + bias;
          }
        }
      }
    }
    __syncthreads();
    const int rbase = half * 128;
    #pragma unroll
    for (int s = 0; s < 8; ++s) {
      const int rowl = s * 16 + (tid >> 5);
      const int c = (tid & 31) * 4;
      f32x4 v = *(const f32x4*)(E + rowl * 132 + c);
      __builtin_nontemporal_store(v, (f32x4*)(out + (long)(rbase + rowl) * NPIX + n0 + c));
    }
  }
}

extern "C" void kernel_launch(void* const* d_in, const int* in_sizes, int n_in,
                              void* d_out, int out_size, void* d_ws, size_t ws_size,
                              hipStream_t stream) {
  const int*   bucket = (const int*)d_in[0];
  const int*   ids    = (const int*)d_in[1];
  const float* W100   = (const float*)d_in[2];
  const float* W10    = (const float*)d_in[3];
  const float* W0     = (const float*)d_in[4];
  const float* fc1w   = (const float*)d_in[5];
  const float* fc1b   = (const float*)d_in[6];
  const float* fc2w   = (const float*)d_in[7];
  const float* fc2b   = (const float*)d_in[8];
  const float* outw   = (const float*)d_in[9];
  const float* outb   = (const float*)d_in[10];
  float* out = (float*)d_out;
  unsigned short* h2w = (unsigned short*)d_ws;  // 256*1024*2B = 512 KB

  embed_mlp_kernel<<<NUM_B, 1024, 0, stream>>>(bucket, ids, W100, W10, W0,
                                               fc1w, fc1b, fc2w, fc2b, h2w);
  out_gemm_kernel<<<NWG, 512, 0, stream>>>(h2w, outw, outb, out);
}